// Round 14
// baseline (126.913 us; speedup 1.0000x reference)
//
#include <hip/hip_runtime.h>

#define NK 1024
#define DD 48              // 4*4*3 floats per code / per block
#define NL (512 * 512)     // 262144 blocks
#define NTILE 32           // 32 code-tiles of 32 codes

// workspace layout (float offsets)
#define WS_CNH 0           // -0.5*cnorm[k]
#define WS_BFRAG 1024
#define NFRAG_TIDS (32 * 3 * 64)   // bprep threads: tiles * ksteps * lanes

typedef __attribute__((ext_vector_type(8)))  _Float16 half8;
typedef __attribute__((ext_vector_type(16))) float    f32x16;

// fp16 2-split: x = h + m*2^-12, m stored scaled by 4096 (fp16-normal range).
__device__ __forceinline__ void split2(float x, _Float16& h, _Float16& m) {
    h = (_Float16)x;
    const float r = x - (float)h;          // exact
    m = (_Float16)(r * 4096.0f);           // exact scale; RN to fp16
}

// cnh[k] = -0.5 * sum_j cb[k][j]^2 (fp32 sequential FMA; *0.5 exact)
__global__ void vq_cnorm_kernel(const float* __restrict__ cb, float* __restrict__ cnh) {
    int k = blockIdx.x * blockDim.x + threadIdx.x;
    if (k >= NK) return;
    const float* row = cb + k * DD;
    float s = 0.0f;
#pragma unroll
    for (int j = 0; j < DD; ++j) s = fmaf(row[j], row[j], s);
    cnh[k] = -0.5f * s;
}

// B prep: tile-major fragment layout. For tile t, frag f in [0,6):
//   frag[(t*6 + f)*64 + lane];  f=0..2 h-level kstep f, f=3..5 m'-level.
// code = t*32 + (lane&31), j = (f%3)*16 + (lane>>5)*8 + e.
__global__ void vq_bprep_kernel(const float* __restrict__ cb, float* __restrict__ ws) {
    int tid = blockIdx.x * blockDim.x + threadIdx.x;
    if (tid >= NFRAG_TIDS) return;
    int lane = tid & 63;
    int s    = (tid >> 6) % 3;
    int t    = tid / (3 * 64);
    int col = lane & 31, lh = lane >> 5;
    const float* src = cb + (t * 32 + col) * DD + s * 16 + lh * 8;
    half8 vh, vm;
#pragma unroll
    for (int e = 0; e < 8; ++e) {
        _Float16 h, m;
        split2(src[e], h, m);
        vh[e] = h; vm[e] = m;
    }
    half8* base = (half8*)(ws + WS_BFRAG);
    base[(t * 6 + s) * 64 + lane]     = vh;
    base[(t * 6 + 3 + s) * 64 + lane] = vm;
}

#define MFMA16 __builtin_amdgcn_mfma_f32_32x32x16_f16

// Cooperative stage of tile T's 6 frags (384 half8) + 32 cn floats into buffer BUF.
#define STAGE(BUF, T) do {                                              \
        const half8* s_ = bsrc + (size_t)(T) * 384;                     \
        lds_b[BUF][tid] = s_[tid];                                      \
        if (tid < 128) lds_b[BUF][256 + tid] = s_[256 + tid];           \
        if (tid < 32)  lds_cn[BUF][tid] = cnp0[(T) * 32 + tid];         \
    } while (0)

// 9 MFMAs (R12's exact order/chains), merge, argmax-select. B from LDS.
#define COMPUTE(BUF, T) do {                                            \
        const half8 Bh0 = lds_b[BUF][lane];                             \
        const half8 Bh1 = lds_b[BUF][64 + lane];                        \
        const half8 Bh2 = lds_b[BUF][128 + lane];                       \
        const half8 Bm0 = lds_b[BUF][192 + lane];                       \
        const half8 Bm1 = lds_b[BUF][256 + lane];                       \
        const half8 Bm2 = lds_b[BUF][320 + lane];                       \
        const float cnh2 = lds_cn[BUF][col];                            \
        f32x16 c1, c2;                                                  \
        _Pragma("unroll")                                               \
        for (int q = 0; q < 16; ++q) { c1[q] = cnh2; c2[q] = 0.0f; }    \
        c2 = MFMA16(Ah[0], Bm0, c2, 0, 0, 0);                           \
        c1 = MFMA16(Ah[0], Bh0, c1, 0, 0, 0);                           \
        c2 = MFMA16(Am[0], Bh0, c2, 0, 0, 0);                           \
        c2 = MFMA16(Ah[1], Bm1, c2, 0, 0, 0);                           \
        c1 = MFMA16(Ah[1], Bh1, c1, 0, 0, 0);                           \
        c2 = MFMA16(Am[1], Bh1, c2, 0, 0, 0);                           \
        c2 = MFMA16(Ah[2], Bm2, c2, 0, 0, 0);                           \
        c1 = MFMA16(Ah[2], Bh2, c1, 0, 0, 0);                           \
        c2 = MFMA16(Am[2], Bh2, c2, 0, 0, 0);                           \
        const f32x16 m = c2 * 0x1p-12f + c1;                            \
        const int kl_ = (T) * 32 + col;                                 \
        _Pragma("unroll")                                               \
        for (int q = 0; q < 16; ++q) if (m[q] > best[q]) bk[q] = kl_;   \
        _Pragma("unroll")                                               \
        for (int q = 0; q < 16; ++q) best[q] = fmaxf(best[q], m[q]);    \
    } while (0)

// Main: wave = 32 blocks (one 32x32 tile) x all 1024 codes.
// fp32 GEMM emulated by 3 fp16 products (hh, hm', m'h); c1 init -cn/2.
// argmin(d2) == argmax(m = dot - cn/2), strict-> keeps first occurrence.
// B-fragments staged per-WG through double-buffered LDS (2-phase pipeline).
__global__ __launch_bounds__(256, 4) void vq_mfma_kernel(const float* __restrict__ img,
                                                         const float* __restrict__ cb,
                                                         const float* __restrict__ ws,
                                                         float* __restrict__ out) {
    __shared__ half8 lds_b[2][384];     // 2 x 6144 B: 6 frags x 64 lanes
    __shared__ float lds_cn[2][32];
    __shared__ int   lds_bk[4 * 32];

    const int tid   = threadIdx.x;
    const int lane  = tid & 63;
    const int wid   = tid >> 6;
    const int wave  = blockIdx.x * 4 + wid;
    const int wbase = wave * 32;
    const int col = lane & 31, lh = lane >> 5;
    const float* cnp0 = ws + WS_CNH;
    const half8* bsrc = (const half8*)(ws + WS_BFRAG);

    // ---- load + split this wave's 32 image blocks into A-fragments ----
    half8 Ah[3], Am[3];
    {
        const int b = wbase + col;
        const int by4 = (b >> 9) * 4, bx = b & 511;
#pragma unroll
        for (int s = 0; s < 3; ++s) {
            const int j0 = s * 16 + lh * 8;
            const int ja = j0, jb = j0 + 4;
            const int ra = (ja * 683) >> 13, ca = ja - 12 * ra;   // j/12, j%12
            const int rb = (jb * 683) >> 13, cb2 = jb - 12 * rb;
            const float4 fa = *(const float4*)(img + ((size_t)(by4 + ra) * 2048 + bx * 4) * 3 + ca);
            const float4 fb = *(const float4*)(img + ((size_t)(by4 + rb) * 2048 + bx * 4) * 3 + cb2);
            const float f[8] = {fa.x, fa.y, fa.z, fa.w, fb.x, fb.y, fb.z, fb.w};
#pragma unroll
            for (int e = 0; e < 8; ++e) {
                _Float16 h, m;
                split2(f[e], h, m);
                Ah[s][e] = h; Am[s][e] = m;
            }
        }
    }

    f32x16 best;
    int bk[16];
#pragma unroll
    for (int q = 0; q < 16; ++q) { best[q] = -__builtin_inff(); bk[q] = 0; }

    // ---- 2-phase K loop: stage t+1 into other buffer while computing t ----
    STAGE(0, 0);
    __syncthreads();
#pragma unroll 1
    for (int t = 0; t < NTILE; t += 2) {
        STAGE(1, t + 1);                       // t+1 <= 31 always
        COMPUTE(0, t);
        __syncthreads();                       // buf1 staged; buf0 reads done
        if (t + 2 < NTILE) STAGE(0, t + 2);
        COMPUTE(1, t + 1);
        __syncthreads();                       // buf0 staged; buf1 reads done
    }

    // ---- cross-lane lexicographic (max m, min k) reduce over 32 cols ----
#pragma unroll
    for (int q = 0; q < 16; ++q) {
        float d = best[q]; int K = bk[q];
#pragma unroll
        for (int mm = 1; mm < 32; mm <<= 1) {
            const float od = __shfl_xor(d, mm, 64);
            const int   ok = __shfl_xor(K, mm, 64);
            const bool tk = (od > d) || (od == d && ok < K);
            d = tk ? od : d; K = tk ? ok : K;
        }
        const int row32 = (q & 3) + 8 * (q >> 2) + 4 * lh;   // verified C-row map
        if ((lane & 31) == q) lds_bk[wid * 32 + row32] = K;
    }
    __syncthreads();

    // ---- gather chosen code (fp32 original), scatter to image layout ----
    const int myk = lds_bk[wid * 32 + col];
    const int b = wbase + col;
    const int by4 = (b >> 9) * 4, bx = b & 511;
    const float4* qp = (const float4*)(cb + (size_t)myk * DD);
#pragma unroll
    for (int rr = 0; rr < 2; ++rr) {
        const int r = lh * 2 + rr;
        float4* op = (float4*)(out + ((size_t)(by4 + r) * 2048 + bx * 4) * 3);
        op[0] = qp[r * 3 + 0];
        op[1] = qp[r * 3 + 1];
        op[2] = qp[r * 3 + 2];
    }
}

extern "C" void kernel_launch(void* const* d_in, const int* in_sizes, int n_in,
                              void* d_out, int out_size, void* d_ws, size_t ws_size,
                              hipStream_t stream) {
    const float* img = (const float*)d_in[0];   // (2048, 2048, 3) fp32
    const float* cb  = (const float*)d_in[1];   // (1024, 16, 3) fp32
    float* out = (float*)d_out;                 // (2048, 2048, 3) fp32
    float* ws  = (float*)d_ws;

    vq_cnorm_kernel<<<(NK + 255) / 256, 256, 0, stream>>>(cb, ws + WS_CNH);
    vq_bprep_kernel<<<(NFRAG_TIDS + 255) / 256, 256, 0, stream>>>(cb, ws);
    vq_mfma_kernel<<<NL / 32 / 4, 256, 0, stream>>>(img, cb, ws, out);
}

// Round 15
// 122.395 us; speedup vs baseline: 1.0369x; 1.0369x over previous
//
#include <hip/hip_runtime.h>

#define NK 1024
#define DD 48              // 4*4*3 floats per code / per block
#define NL (512 * 512)     // 262144 blocks
#define NTILE 32           // 32 code-tiles of 32 codes

// workspace layout (float offsets)
#define WS_CNH 0           // -0.5*cnorm[k]
#define WS_BFRAG 1024
#define NFRAG_TIDS (32 * 3 * 64)   // bprep threads: tiles * ksteps * lanes

typedef __attribute__((ext_vector_type(8)))  _Float16 half8;
typedef __attribute__((ext_vector_type(16))) float    f32x16;

// fp16 2-split: x = h + m*2^-12, m stored scaled by 4096 (fp16-normal range).
__device__ __forceinline__ void split2(float x, _Float16& h, _Float16& m) {
    h = (_Float16)x;
    const float r = x - (float)h;          // exact
    m = (_Float16)(r * 4096.0f);           // exact scale; RN to fp16
}

// cnh[k] = -0.5 * sum_j cb[k][j]^2 (fp32 sequential FMA; *0.5 exact)
__global__ void vq_cnorm_kernel(const float* __restrict__ cb, float* __restrict__ cnh) {
    int k = blockIdx.x * blockDim.x + threadIdx.x;
    if (k >= NK) return;
    const float* row = cb + k * DD;
    float s = 0.0f;
#pragma unroll
    for (int j = 0; j < DD; ++j) s = fmaf(row[j], row[j], s);
    cnh[k] = -0.5f * s;
}

// B prep: tile-major fragment layout. For tile t:
//   frag[(t*6 + s)*64 + lane]     = h-level, kstep s
//   frag[(t*6 + 3 + s)*64 + lane] = m'-level, kstep s
// code = t*32 + (lane&31), j = s*16 + (lane>>5)*8 + e.
__global__ void vq_bprep_kernel(const float* __restrict__ cb, float* __restrict__ ws) {
    int tid = blockIdx.x * blockDim.x + threadIdx.x;
    if (tid >= NFRAG_TIDS) return;
    int lane = tid & 63;
    int s    = (tid >> 6) % 3;
    int t    = tid / (3 * 64);
    int col = lane & 31, lh = lane >> 5;
    const float* src = cb + (t * 32 + col) * DD + s * 16 + lh * 8;
    half8 vh, vm;
#pragma unroll
    for (int e = 0; e < 8; ++e) {
        _Float16 h, m;
        split2(src[e], h, m);
        vh[e] = h; vm[e] = m;
    }
    half8* base = (half8*)(ws + WS_BFRAG);
    base[(t * 6 + s) * 64 + lane]     = vh;
    base[(t * 6 + 3 + s) * 64 + lane] = vm;
}

#define MFMA16 __builtin_amdgcn_mfma_f32_32x32x16_f16

// Main: wave = 32 blocks (one 32x32 tile) x all 1024 codes.
// fp32 GEMM emulated by 3 fp16 products in 3 ROUND-ROBIN chains:
//   c1  = hh   (init -cn/2: embeds the codebook norm)
//   c2a = hm'  (x 2^-12)
//   c2b = m'h  (x 2^-12)
// Dep distance = 3 MFMAs (~97 cy) on every chain -> covers MFMA latency.
// Merge grouping (c2a+c2b) validated bit-exact in R13 (absmax=0).
// argmin(d2) == argmax(m = dot - cn/2), strict-> keeps first occurrence.
__global__ __launch_bounds__(256, 4) void vq_mfma_kernel(const float* __restrict__ img,
                                                         const float* __restrict__ cb,
                                                         const float* __restrict__ ws,
                                                         float* __restrict__ out) {
    __shared__ int lds_bk[4 * 32];
    const int lane  = threadIdx.x & 63;
    const int wid   = threadIdx.x >> 6;
    const int wave  = blockIdx.x * 4 + wid;
    const int wbase = wave * 32;
    const int col = lane & 31, lh = lane >> 5;
    const float* cnp  = ws + WS_CNH + col;              // -cn/2 stream
    const half8* bp   = (const half8*)(ws + WS_BFRAG) + lane;

    // ---- load + split this wave's 32 image blocks into A-fragments ----
    half8 Ah[3], Am[3];
    {
        const int b = wbase + col;
        const int by4 = (b >> 9) * 4, bx = b & 511;
#pragma unroll
        for (int s = 0; s < 3; ++s) {
            const int j0 = s * 16 + lh * 8;
            const int ja = j0, jb = j0 + 4;
            const int ra = (ja * 683) >> 13, ca = ja - 12 * ra;   // j/12, j%12
            const int rb = (jb * 683) >> 13, cb2 = jb - 12 * rb;
            const float4 fa = *(const float4*)(img + ((size_t)(by4 + ra) * 2048 + bx * 4) * 3 + ca);
            const float4 fb = *(const float4*)(img + ((size_t)(by4 + rb) * 2048 + bx * 4) * 3 + cb2);
            const float f[8] = {fa.x, fa.y, fa.z, fa.w, fb.x, fb.y, fb.z, fb.w};
#pragma unroll
            for (int e = 0; e < 8; ++e) {
                _Float16 h, m;
                split2(f[e], h, m);
                Ah[s][e] = h; Am[s][e] = m;
            }
        }
    }

    f32x16 best;
    int bk[16];
#pragma unroll
    for (int q = 0; q < 16; ++q) { best[q] = -__builtin_inff(); bk[q] = 0; }

#pragma unroll 1
    for (int t = 0; t < NTILE; ++t) {
        const half8* pt = bp + t * 384;          // 6 frags, imm offsets
        const half8 Bh0 = pt[0],   Bh1 = pt[64],  Bh2 = pt[128];
        const half8 Bm0 = pt[192], Bm1 = pt[256], Bm2 = pt[320];
        const float cnh2 = cnp[t * 32];          // -cn/2
        const int   kl   = t * 32 + col;

        // 3 round-robin chains, dep distance 3 (~97 cy >= MFMA latency)
        f32x16 c1, c2a, c2b;
#pragma unroll
        for (int q = 0; q < 16; ++q) { c1[q] = cnh2; c2a[q] = 0.0f; c2b[q] = 0.0f; }

        c1  = MFMA16(Ah[0], Bh0, c1,  0, 0, 0);
        c2a = MFMA16(Ah[0], Bm0, c2a, 0, 0, 0);
        c2b = MFMA16(Am[0], Bh0, c2b, 0, 0, 0);
        c1  = MFMA16(Ah[1], Bh1, c1,  0, 0, 0);
        c2a = MFMA16(Ah[1], Bm1, c2a, 0, 0, 0);
        c2b = MFMA16(Am[1], Bh1, c2b, 0, 0, 0);
        c1  = MFMA16(Ah[2], Bh2, c1,  0, 0, 0);
        c2a = MFMA16(Ah[2], Bm2, c2a, 0, 0, 0);
        c2b = MFMA16(Am[2], Bh2, c2b, 0, 0, 0);

        // vector merge (packed fp32): m = (c2a + c2b)*2^-12 + c1
        const f32x16 m = (c2a + c2b) * 0x1p-12f + c1;

        // bk select (scalar cmp+cndmask), then packed max update
#pragma unroll
        for (int q = 0; q < 16; ++q) if (m[q] > best[q]) bk[q] = kl;
#pragma unroll
        for (int q = 0; q < 16; ++q) best[q] = fmaxf(best[q], m[q]);
    }

    // ---- cross-lane lexicographic (max m, min k) reduce over 32 cols ----
#pragma unroll
    for (int q = 0; q < 16; ++q) {
        float d = best[q]; int K = bk[q];
#pragma unroll
        for (int mm = 1; mm < 32; mm <<= 1) {
            const float od = __shfl_xor(d, mm, 64);
            const int   ok = __shfl_xor(K, mm, 64);
            const bool tk = (od > d) || (od == d && ok < K);
            d = tk ? od : d; K = tk ? ok : K;
        }
        const int row32 = (q & 3) + 8 * (q >> 2) + 4 * lh;   // verified C-row map
        if ((lane & 31) == q) lds_bk[wid * 32 + row32] = K;
    }
    __syncthreads();

    // ---- gather chosen code (fp32 original), scatter to image layout ----
    const int myk = lds_bk[wid * 32 + col];
    const int b = wbase + col;
    const int by4 = (b >> 9) * 4, bx = b & 511;
    const float4* qp = (const float4*)(cb + (size_t)myk * DD);
#pragma unroll
    for (int rr = 0; rr < 2; ++rr) {
        const int r = lh * 2 + rr;
        float4* op = (float4*)(out + ((size_t)(by4 + r) * 2048 + bx * 4) * 3);
        op[0] = qp[r * 3 + 0];
        op[1] = qp[r * 3 + 1];
        op[2] = qp[r * 3 + 2];
    }
}

extern "C" void kernel_launch(void* const* d_in, const int* in_sizes, int n_in,
                              void* d_out, int out_size, void* d_ws, size_t ws_size,
                              hipStream_t stream) {
    const float* img = (const float*)d_in[0];   // (2048, 2048, 3) fp32
    const float* cb  = (const float*)d_in[1];   // (1024, 16, 3) fp32
    float* out = (float*)d_out;                 // (2048, 2048, 3) fp32
    float* ws  = (float*)d_ws;

    vq_cnorm_kernel<<<(NK + 255) / 256, 256, 0, stream>>>(cb, ws + WS_CNH);
    vq_bprep_kernel<<<(NFRAG_TIDS + 255) / 256, 256, 0, stream>>>(cb, ws);
    vq_mfma_kernel<<<NL / 32 / 4, 256, 0, stream>>>(img, cb, ws, out);
}

// Round 16
// 120.072 us; speedup vs baseline: 1.0570x; 1.0193x over previous
//
#include <hip/hip_runtime.h>

#define NK 1024
#define DD 48              // 4*4*3 floats per code / per block
#define NL (512 * 512)     // 262144 blocks
#define NTILE 32           // 32 code-tiles of 32 codes

// workspace layout (float offsets)
#define WS_CNH 0           // -0.5*cnorm[k]
#define WS_BFRAG 1024
#define NFRAG_TIDS (32 * 3 * 64)   // bprep threads: tiles * ksteps * lanes

typedef __attribute__((ext_vector_type(8)))  _Float16 half8;
typedef __attribute__((ext_vector_type(16))) float    f32x16;

// fp16 2-split: x = h + m*2^-12, m stored scaled by 4096 (fp16-normal range).
__device__ __forceinline__ void split2(float x, _Float16& h, _Float16& m) {
    h = (_Float16)x;
    const float r = x - (float)h;          // exact
    m = (_Float16)(r * 4096.0f);           // exact scale; RN to fp16
}

// cnh[k] = -0.5 * sum_j cb[k][j]^2 (fp32 sequential FMA; *0.5 exact)
__global__ void vq_cnorm_kernel(const float* __restrict__ cb, float* __restrict__ cnh) {
    int k = blockIdx.x * blockDim.x + threadIdx.x;
    if (k >= NK) return;
    const float* row = cb + k * DD;
    float s = 0.0f;
#pragma unroll
    for (int j = 0; j < DD; ++j) s = fmaf(row[j], row[j], s);
    cnh[k] = -0.5f * s;
}

// B prep: tile-major fragment layout. For tile t:
//   frag[(t*6 + s)*64 + lane]     = h-level, kstep s
//   frag[(t*6 + 3 + s)*64 + lane] = m'-level, kstep s
// code = t*32 + (lane&31), j = s*16 + (lane>>5)*8 + e.
__global__ void vq_bprep_kernel(const float* __restrict__ cb, float* __restrict__ ws) {
    int tid = blockIdx.x * blockDim.x + threadIdx.x;
    if (tid >= NFRAG_TIDS) return;
    int lane = tid & 63;
    int s    = (tid >> 6) % 3;
    int t    = tid / (3 * 64);
    int col = lane & 31, lh = lane >> 5;
    const float* src = cb + (t * 32 + col) * DD + s * 16 + lh * 8;
    half8 vh, vm;
#pragma unroll
    for (int e = 0; e < 8; ++e) {
        _Float16 h, m;
        split2(src[e], h, m);
        vh[e] = h; vm[e] = m;
    }
    half8* base = (half8*)(ws + WS_BFRAG);
    base[(t * 6 + s) * 64 + lane]     = vh;
    base[(t * 6 + 3 + s) * 64 + lane] = vm;
}

#define MFMA16 __builtin_amdgcn_mfma_f32_32x32x16_f16

// Main: wave = 64 blocks (TWO 32x32 C-tiles sharing each B tile) x 1024 codes.
// fp32 GEMM emulated by 3 fp16 products in 2 chains per tile (R12's exact
// per-tile scheme, absmax=0 validated); T0/T1 interleave doubles dep distance
// and amortizes each B-fragment load over 2x the MFMAs.
// argmin(d2) == argmax(m = dot - cn/2), strict-> keeps first occurrence.
__global__ __launch_bounds__(256, 2) void vq_mfma_kernel(const float* __restrict__ img,
                                                         const float* __restrict__ cb,
                                                         const float* __restrict__ ws,
                                                         float* __restrict__ out) {
    __shared__ int lds_bk[4 * 64];
    const int lane  = threadIdx.x & 63;
    const int wid   = threadIdx.x >> 6;
    const int wave  = blockIdx.x * 4 + wid;
    const int wbase = wave * 64;
    const int col = lane & 31, lh = lane >> 5;
    const float* cnp  = ws + WS_CNH + col;              // -cn/2 stream
    const half8* bp   = (const half8*)(ws + WS_BFRAG) + lane;

    // ---- load + split 2 tiles' image blocks into A-fragments (48 VGPR) ----
    half8 Ah[2][3], Am[2][3];
#pragma unroll
    for (int T = 0; T < 2; ++T) {
        const int b = wbase + T * 32 + col;
        const int by4 = (b >> 9) * 4, bx = b & 511;
#pragma unroll
        for (int s = 0; s < 3; ++s) {
            const int j0 = s * 16 + lh * 8;
            const int ja = j0, jb = j0 + 4;
            const int ra = (ja * 683) >> 13, ca = ja - 12 * ra;   // j/12, j%12
            const int rb = (jb * 683) >> 13, cb2 = jb - 12 * rb;
            const float4 fa = *(const float4*)(img + ((size_t)(by4 + ra) * 2048 + bx * 4) * 3 + ca);
            const float4 fb = *(const float4*)(img + ((size_t)(by4 + rb) * 2048 + bx * 4) * 3 + cb2);
            const float f[8] = {fa.x, fa.y, fa.z, fa.w, fb.x, fb.y, fb.z, fb.w};
#pragma unroll
            for (int e = 0; e < 8; ++e) {
                _Float16 h, m;
                split2(f[e], h, m);
                Ah[T][s][e] = h; Am[T][s][e] = m;
            }
        }
    }

    f32x16 best0, best1;
    int bk0[16], bk1[16];
#pragma unroll
    for (int q = 0; q < 16; ++q) {
        best0[q] = -__builtin_inff(); best1[q] = -__builtin_inff();
        bk0[q] = 0; bk1[q] = 0;
    }

#pragma unroll 1
    for (int t = 0; t < NTILE; ++t) {
        const half8* pt = bp + t * 384;          // 6 frags, imm offsets
        const half8 Bh0 = pt[0],   Bh1 = pt[64],  Bh2 = pt[128];
        const half8 Bm0 = pt[192], Bm1 = pt[256], Bm2 = pt[320];
        const float cnh2 = cnp[t * 32];          // -cn/2
        const int   kl   = t * 32 + col;

        // 4 chains (c1,c2 per tile), T-interleaved: dep distance >= 2
        f32x16 c1_0, c2_0, c1_1, c2_1;
#pragma unroll
        for (int q = 0; q < 16; ++q) {
            c1_0[q] = cnh2; c2_0[q] = 0.0f;
            c1_1[q] = cnh2; c2_1[q] = 0.0f;
        }

        c2_0 = MFMA16(Ah[0][0], Bm0, c2_0, 0, 0, 0);
        c2_1 = MFMA16(Ah[1][0], Bm0, c2_1, 0, 0, 0);
        c1_0 = MFMA16(Ah[0][0], Bh0, c1_0, 0, 0, 0);
        c1_1 = MFMA16(Ah[1][0], Bh0, c1_1, 0, 0, 0);
        c2_0 = MFMA16(Am[0][0], Bh0, c2_0, 0, 0, 0);
        c2_1 = MFMA16(Am[1][0], Bh0, c2_1, 0, 0, 0);
        c2_0 = MFMA16(Ah[0][1], Bm1, c2_0, 0, 0, 0);
        c2_1 = MFMA16(Ah[1][1], Bm1, c2_1, 0, 0, 0);
        c1_0 = MFMA16(Ah[0][1], Bh1, c1_0, 0, 0, 0);
        c1_1 = MFMA16(Ah[1][1], Bh1, c1_1, 0, 0, 0);
        c2_0 = MFMA16(Am[0][1], Bh1, c2_0, 0, 0, 0);
        c2_1 = MFMA16(Am[1][1], Bh1, c2_1, 0, 0, 0);
        c2_0 = MFMA16(Ah[0][2], Bm2, c2_0, 0, 0, 0);
        c2_1 = MFMA16(Ah[1][2], Bm2, c2_1, 0, 0, 0);
        c1_0 = MFMA16(Ah[0][2], Bh2, c1_0, 0, 0, 0);
        c1_1 = MFMA16(Ah[1][2], Bh2, c1_1, 0, 0, 0);
        c2_0 = MFMA16(Am[0][2], Bh2, c2_0, 0, 0, 0);
        c2_1 = MFMA16(Am[1][2], Bh2, c2_1, 0, 0, 0);

        // vector merge (packed fp32): m = c2*2^-12 + c1   (R12's exact form)
        const f32x16 m0 = c2_0 * 0x1p-12f + c1_0;
        const f32x16 m1 = c2_1 * 0x1p-12f + c1_1;

#pragma unroll
        for (int q = 0; q < 16; ++q) if (m0[q] > best0[q]) bk0[q] = kl;
#pragma unroll
        for (int q = 0; q < 16; ++q) best0[q] = fmaxf(best0[q], m0[q]);
#pragma unroll
        for (int q = 0; q < 16; ++q) if (m1[q] > best1[q]) bk1[q] = kl;
#pragma unroll
        for (int q = 0; q < 16; ++q) best1[q] = fmaxf(best1[q], m1[q]);
    }

    // ---- cross-lane lexicographic (max m, min k) reduce over 32 cols ----
#pragma unroll
    for (int q = 0; q < 16; ++q) {
        float d0 = best0[q]; int K0 = bk0[q];
        float d1 = best1[q]; int K1 = bk1[q];
#pragma unroll
        for (int mm = 1; mm < 32; mm <<= 1) {
            float od = __shfl_xor(d0, mm, 64); int ok = __shfl_xor(K0, mm, 64);
            bool tk = (od > d0) || (od == d0 && ok < K0);
            d0 = tk ? od : d0; K0 = tk ? ok : K0;
            od = __shfl_xor(d1, mm, 64); ok = __shfl_xor(K1, mm, 64);
            tk = (od > d1) || (od == d1 && ok < K1);
            d1 = tk ? od : d1; K1 = tk ? ok : K1;
        }
        const int row32 = (q & 3) + 8 * (q >> 2) + 4 * lh;   // verified C-row map
        if ((lane & 31) == q) {
            lds_bk[wid * 64 + row32]      = K0;   // T=0 blocks
            lds_bk[wid * 64 + 32 + row32] = K1;   // T=1 blocks
        }
    }
    __syncthreads();

    // ---- gather chosen code (fp32 original), scatter to image layout ----
    const int myk = lds_bk[wid * 64 + lane];     // block wbase+lane
    const int b = wbase + lane;
    const int by4 = (b >> 9) * 4, bx = b & 511;
    const float4* qp = (const float4*)(cb + (size_t)myk * DD);
#pragma unroll
    for (int r = 0; r < 4; ++r) {
        float4* op = (float4*)(out + ((size_t)(by4 + r) * 2048 + bx * 4) * 3);
        op[0] = qp[r * 3 + 0];
        op[1] = qp[r * 3 + 1];
        op[2] = qp[r * 3 + 2];
    }
}

extern "C" void kernel_launch(void* const* d_in, const int* in_sizes, int n_in,
                              void* d_out, int out_size, void* d_ws, size_t ws_size,
                              hipStream_t stream) {
    const float* img = (const float*)d_in[0];   // (2048, 2048, 3) fp32
    const float* cb  = (const float*)d_in[1];   // (1024, 16, 3) fp32
    float* out = (float*)d_out;                 // (2048, 2048, 3) fp32
    float* ws  = (float*)d_ws;

    vq_cnorm_kernel<<<(NK + 255) / 256, 256, 0, stream>>>(cb, ws + WS_CNH);
    vq_bprep_kernel<<<(NFRAG_TIDS + 255) / 256, 256, 0, stream>>>(cb, ws);
    vq_mfma_kernel<<<NL / 64 / 4, 256, 0, stream>>>(img, cb, ws, out);
}

// Round 17
// 118.523 us; speedup vs baseline: 1.0708x; 1.0131x over previous
//
#include <hip/hip_runtime.h>

#define NK 1024
#define DD 48              // 4*4*3 floats per code / per block
#define NL (512 * 512)     // 262144 blocks
#define NTILE 32           // 32 code-tiles of 32 codes

// workspace layout (float offsets)
#define WS_CNH 0           // -0.5*cnorm[k]
#define WS_BFRAG 1024
#define NFRAG_TIDS (32 * 3 * 64)   // bprep threads: tiles * ksteps * lanes

typedef __attribute__((ext_vector_type(8)))  _Float16 half8;
typedef __attribute__((ext_vector_type(16))) float    f32x16;

// fp16 2-split: x = h + m*2^-12, m stored scaled by 4096 (fp16-normal range).
__device__ __forceinline__ void split2(float x, _Float16& h, _Float16& m) {
    h = (_Float16)x;
    const float r = x - (float)h;          // exact
    m = (_Float16)(r * 4096.0f);           // exact scale; RN to fp16
}

// cnh[k] = -0.5 * sum_j cb[k][j]^2 (fp32 sequential FMA; *0.5 exact)
__global__ void vq_cnorm_kernel(const float* __restrict__ cb, float* __restrict__ cnh) {
    int k = blockIdx.x * blockDim.x + threadIdx.x;
    if (k >= NK) return;
    const float* row = cb + k * DD;
    float s = 0.0f;
#pragma unroll
    for (int j = 0; j < DD; ++j) s = fmaf(row[j], row[j], s);
    cnh[k] = -0.5f * s;
}

// B prep: tile-major fragment layout. For tile t:
//   frag[(t*6 + s)*64 + lane]     = h-level, kstep s
//   frag[(t*6 + 3 + s)*64 + lane] = m'-level, kstep s
// code = t*32 + (lane&31), j = s*16 + (lane>>5)*8 + e.
__global__ void vq_bprep_kernel(const float* __restrict__ cb, float* __restrict__ ws) {
    int tid = blockIdx.x * blockDim.x + threadIdx.x;
    if (tid >= NFRAG_TIDS) return;
    int lane = tid & 63;
    int s    = (tid >> 6) % 3;
    int t    = tid / (3 * 64);
    int col = lane & 31, lh = lane >> 5;
    const float* src = cb + (t * 32 + col) * DD + s * 16 + lh * 8;
    half8 vh, vm;
#pragma unroll
    for (int e = 0; e < 8; ++e) {
        _Float16 h, m;
        split2(src[e], h, m);
        vh[e] = h; vm[e] = m;
    }
    half8* base = (half8*)(ws + WS_BFRAG);
    base[(t * 6 + s) * 64 + lane]     = vh;
    base[(t * 6 + 3 + s) * 64 + lane] = vm;
}

#define MFMA16 __builtin_amdgcn_mfma_f32_32x32x16_f16

// Main: wave = 32 blocks (one 32x32 tile) x all 1024 codes.
// fp32 GEMM emulated by 3 fp16 products in 2 scale-separated chains:
//   c1 = hh            (init -cn/2: embeds the codebook norm)
//   c2 = hm' + m'h     (x 2^-12)
// (m'm' dropped: RMS ~3e-7 on the dot, below the validated fp16-truncation
//  noise floor that flipped zero argmins in R10/R11.)
// argmin(d2) == argmax(m = dot - cn/2), strict-> keeps first occurrence.
// NOTE (R13-R16): do NOT add staging/ping-pong/extra chains/2-tile ILP here;
// all four variants measured slower (122-127 vs 118).
__global__ __launch_bounds__(256, 4) void vq_mfma_kernel(const float* __restrict__ img,
                                                         const float* __restrict__ cb,
                                                         const float* __restrict__ ws,
                                                         float* __restrict__ out) {
    __shared__ int lds_bk[4 * 32];
    const int lane  = threadIdx.x & 63;
    const int wid   = threadIdx.x >> 6;
    const int wave  = blockIdx.x * 4 + wid;
    const int wbase = wave * 32;
    const int col = lane & 31, lh = lane >> 5;
    const float* cnp  = ws + WS_CNH + col;              // -cn/2 stream
    const half8* bp   = (const half8*)(ws + WS_BFRAG) + lane;

    // ---- load + split this wave's 32 image blocks into A-fragments ----
    half8 Ah[3], Am[3];
    {
        const int b = wbase + col;
        const int by4 = (b >> 9) * 4, bx = b & 511;
#pragma unroll
        for (int s = 0; s < 3; ++s) {
            const int j0 = s * 16 + lh * 8;
            const int ja = j0, jb = j0 + 4;
            const int ra = (ja * 683) >> 13, ca = ja - 12 * ra;   // j/12, j%12
            const int rb = (jb * 683) >> 13, cb2 = jb - 12 * rb;
            const float4 fa = *(const float4*)(img + ((size_t)(by4 + ra) * 2048 + bx * 4) * 3 + ca);
            const float4 fb = *(const float4*)(img + ((size_t)(by4 + rb) * 2048 + bx * 4) * 3 + cb2);
            const float f[8] = {fa.x, fa.y, fa.z, fa.w, fb.x, fb.y, fb.z, fb.w};
#pragma unroll
            for (int e = 0; e < 8; ++e) {
                _Float16 h, m;
                split2(f[e], h, m);
                Ah[s][e] = h; Am[s][e] = m;
            }
        }
    }

    f32x16 best;
    int bk[16];
#pragma unroll
    for (int q = 0; q < 16; ++q) { best[q] = -__builtin_inff(); bk[q] = 0; }

#pragma unroll 1
    for (int t = 0; t < NTILE; ++t) {
        const half8* pt = bp + t * 384;          // 6 frags, imm offsets
        const half8 Bh0 = pt[0],   Bh1 = pt[64],  Bh2 = pt[128];
        const half8 Bm0 = pt[192], Bm1 = pt[256], Bm2 = pt[320];
        const float cnh2 = cnp[t * 32];          // -cn/2
        const int   kl   = t * 32 + col;

        f32x16 c1, c2;
#pragma unroll
        for (int q = 0; q < 16; ++q) { c1[q] = cnh2; c2[q] = 0.0f; }

        c2 = MFMA16(Ah[0], Bm0, c2, 0, 0, 0);
        c1 = MFMA16(Ah[0], Bh0, c1, 0, 0, 0);
        c2 = MFMA16(Am[0], Bh0, c2, 0, 0, 0);
        c2 = MFMA16(Ah[1], Bm1, c2, 0, 0, 0);
        c1 = MFMA16(Ah[1], Bh1, c1, 0, 0, 0);
        c2 = MFMA16(Am[1], Bh1, c2, 0, 0, 0);
        c2 = MFMA16(Ah[2], Bm2, c2, 0, 0, 0);
        c1 = MFMA16(Ah[2], Bh2, c1, 0, 0, 0);
        c2 = MFMA16(Am[2], Bh2, c2, 0, 0, 0);

        // vector merge (packed fp32): m = c2*2^-12 + c1
        const f32x16 m = c2 * 0x1p-12f + c1;

        // bk select (scalar cmp+cndmask), then packed max update
#pragma unroll
        for (int q = 0; q < 16; ++q) if (m[q] > best[q]) bk[q] = kl;
#pragma unroll
        for (int q = 0; q < 16; ++q) best[q] = fmaxf(best[q], m[q]);
    }

    // ---- cross-lane lexicographic (max m, min k) reduce over 32 cols ----
#pragma unroll
    for (int q = 0; q < 16; ++q) {
        float d = best[q]; int K = bk[q];
#pragma unroll
        for (int mm = 1; mm < 32; mm <<= 1) {
            const float od = __shfl_xor(d, mm, 64);
            const int   ok = __shfl_xor(K, mm, 64);
            const bool tk = (od > d) || (od == d && ok < K);
            d = tk ? od : d; K = tk ? ok : K;
        }
        const int row32 = (q & 3) + 8 * (q >> 2) + 4 * lh;   // verified C-row map
        if ((lane & 31) == q) lds_bk[wid * 32 + row32] = K;
    }
    __syncthreads();

    // ---- gather chosen code (fp32 original), scatter to image layout ----
    const int myk = lds_bk[wid * 32 + col];
    const int b = wbase + col;
    const int by4 = (b >> 9) * 4, bx = b & 511;
    const float4* qp = (const float4*)(cb + (size_t)myk * DD);
#pragma unroll
    for (int rr = 0; rr < 2; ++rr) {
        const int r = lh * 2 + rr;
        float4* op = (float4*)(out + ((size_t)(by4 + r) * 2048 + bx * 4) * 3);
        op[0] = qp[r * 3 + 0];
        op[1] = qp[r * 3 + 1];
        op[2] = qp[r * 3 + 2];
    }
}

extern "C" void kernel_launch(void* const* d_in, const int* in_sizes, int n_in,
                              void* d_out, int out_size, void* d_ws, size_t ws_size,
                              hipStream_t stream) {
    const float* img = (const float*)d_in[0];   // (2048, 2048, 3) fp32
    const float* cb  = (const float*)d_in[1];   // (1024, 16, 3) fp32
    float* out = (float*)d_out;                 // (2048, 2048, 3) fp32
    float* ws  = (float*)d_ws;

    vq_cnorm_kernel<<<(NK + 255) / 256, 256, 0, stream>>>(cb, ws + WS_CNH);
    vq_bprep_kernel<<<(NFRAG_TIDS + 255) / 256, 256, 0, stream>>>(cb, ws);
    vq_mfma_kernel<<<NL / 32 / 4, 256, 0, stream>>>(img, cb, ws, out);
}

// Round 18
// 117.313 us; speedup vs baseline: 1.0818x; 1.0103x over previous
//
#include <hip/hip_runtime.h>

#define NK 1024
#define DD 48              // 4*4*3 floats per code / per block
#define NL (512 * 512)     // 262144 blocks
#define NTILE 32           // 32 code-tiles of 32 codes

// workspace layout (float offsets)
#define WS_CNH 0           // -0.5*cnorm[k]
#define WS_BFRAG 1024
#define NFRAG_TIDS (32 * 3 * 64)   // bprep threads: tiles * ksteps * lanes

typedef __attribute__((ext_vector_type(8)))  _Float16 half8;
typedef __attribute__((ext_vector_type(16))) float    f32x16;

// fp16 2-split: x = h + m*2^-12, m stored scaled by 4096 (fp16-normal range).
__device__ __forceinline__ void split2(float x, _Float16& h, _Float16& m) {
    h = (_Float16)x;
    const float r = x - (float)h;          // exact
    m = (_Float16)(r * 4096.0f);           // exact scale; RN to fp16
}

// cnh[k] = -0.5 * sum_j cb[k][j]^2 (fp32 sequential FMA; *0.5 exact)
__global__ void vq_cnorm_kernel(const float* __restrict__ cb, float* __restrict__ cnh) {
    int k = blockIdx.x * blockDim.x + threadIdx.x;
    if (k >= NK) return;
    const float* row = cb + k * DD;
    float s = 0.0f;
#pragma unroll
    for (int j = 0; j < DD; ++j) s = fmaf(row[j], row[j], s);
    cnh[k] = -0.5f * s;
}

// B prep: tile-major fragment layout. For tile t:
//   frag[(t*6 + s)*64 + lane]     = h-level, kstep s
//   frag[(t*6 + 3 + s)*64 + lane] = m'-level, kstep s
// code = t*32 + (lane&31), j = s*16 + (lane>>5)*8 + e.
__global__ void vq_bprep_kernel(const float* __restrict__ cb, float* __restrict__ ws) {
    int tid = blockIdx.x * blockDim.x + threadIdx.x;
    if (tid >= NFRAG_TIDS) return;
    int lane = tid & 63;
    int s    = (tid >> 6) % 3;
    int t    = tid / (3 * 64);
    int col = lane & 31, lh = lane >> 5;
    const float* src = cb + (t * 32 + col) * DD + s * 16 + lh * 8;
    half8 vh, vm;
#pragma unroll
    for (int e = 0; e < 8; ++e) {
        _Float16 h, m;
        split2(src[e], h, m);
        vh[e] = h; vm[e] = m;
    }
    half8* base = (half8*)(ws + WS_BFRAG);
    base[(t * 6 + s) * 64 + lane]     = vh;
    base[(t * 6 + 3 + s) * 64 + lane] = vm;
}

#define MFMA16 __builtin_amdgcn_mfma_f32_32x32x16_f16

// Main: wave = 32 blocks (one 32x32 tile) x all 1024 codes.
// fp32 GEMM emulated by 3 fp16 products in 2 scale-separated chains:
//   c1 = hh            (init -cn/2: embeds the codebook norm)
//   c2 = hm' + m'h     (x 2^-12)
// argmin(d2) == argmax(m = dot - cn/2), strict-> keeps first occurrence.
// IN-PLACE PREFETCH (vs R13's rejected ping-pong): tile t+1's B-fragments are
// loaded into the SAME named registers right after tile t's MFMAs consume
// them (operands read at issue) -> loads fly during the epilogue, zero extra
// registers, occupancy preserved. cn is carried one iteration ahead so the
// c1-init (critical path into the first MFMA) never waits on a fresh load.
// NOTE (R13-R16): buffer ping-pong / LDS staging / 3 chains / 2-tile ILP all
// measured slower (122-127 vs 118).
__global__ __launch_bounds__(256, 4) void vq_mfma_kernel(const float* __restrict__ img,
                                                         const float* __restrict__ cb,
                                                         const float* __restrict__ ws,
                                                         float* __restrict__ out) {
    __shared__ int lds_bk[4 * 32];
    const int lane  = threadIdx.x & 63;
    const int wid   = threadIdx.x >> 6;
    const int wave  = blockIdx.x * 4 + wid;
    const int wbase = wave * 32;
    const int col = lane & 31, lh = lane >> 5;
    const float* cnp  = ws + WS_CNH + col;              // -cn/2 stream
    const half8* bp   = (const half8*)(ws + WS_BFRAG) + lane;

    // ---- load + split this wave's 32 image blocks into A-fragments ----
    half8 Ah[3], Am[3];
    {
        const int b = wbase + col;
        const int by4 = (b >> 9) * 4, bx = b & 511;
#pragma unroll
        for (int s = 0; s < 3; ++s) {
            const int j0 = s * 16 + lh * 8;
            const int ja = j0, jb = j0 + 4;
            const int ra = (ja * 683) >> 13, ca = ja - 12 * ra;   // j/12, j%12
            const int rb = (jb * 683) >> 13, cb2 = jb - 12 * rb;
            const float4 fa = *(const float4*)(img + ((size_t)(by4 + ra) * 2048 + bx * 4) * 3 + ca);
            const float4 fb = *(const float4*)(img + ((size_t)(by4 + rb) * 2048 + bx * 4) * 3 + cb2);
            const float f[8] = {fa.x, fa.y, fa.z, fa.w, fb.x, fb.y, fb.z, fb.w};
#pragma unroll
            for (int e = 0; e < 8; ++e) {
                _Float16 h, m;
                split2(f[e], h, m);
                Ah[s][e] = h; Am[s][e] = m;
            }
        }
    }

    f32x16 best;
    int bk[16];
#pragma unroll
    for (int q = 0; q < 16; ++q) { best[q] = -__builtin_inff(); bk[q] = 0; }

    // ---- prologue: tile 0's B-fragments + cn ----
    half8 Bh0 = bp[0],   Bh1 = bp[64],  Bh2 = bp[128];
    half8 Bm0 = bp[192], Bm1 = bp[256], Bm2 = bp[320];
    float cn_cur = cnp[0];

#pragma unroll 1
    for (int t = 0; t < NTILE; ++t) {
        const int tn = (t + 1) & 31;             // wraps to 0 at t=31 (unused)
        const float cn_nxt = cnp[tn * 32];       // issue early, independent
        const int   kl     = t * 32 + col;

        f32x16 c1, c2;
#pragma unroll
        for (int q = 0; q < 16; ++q) { c1[q] = cn_cur; c2[q] = 0.0f; }

        c2 = MFMA16(Ah[0], Bm0, c2, 0, 0, 0);
        c1 = MFMA16(Ah[0], Bh0, c1, 0, 0, 0);
        c2 = MFMA16(Am[0], Bh0, c2, 0, 0, 0);
        c2 = MFMA16(Ah[1], Bm1, c2, 0, 0, 0);
        c1 = MFMA16(Ah[1], Bh1, c1, 0, 0, 0);
        c2 = MFMA16(Am[1], Bh1, c2, 0, 0, 0);
        c2 = MFMA16(Ah[2], Bm2, c2, 0, 0, 0);
        c1 = MFMA16(Ah[2], Bh2, c1, 0, 0, 0);
        c2 = MFMA16(Am[2], Bh2, c2, 0, 0, 0);

        // in-place prefetch of tile t+1 (operands above already consumed)
        const half8* pn = bp + tn * 384;
        Bh0 = pn[0];   Bh1 = pn[64];  Bh2 = pn[128];
        Bm0 = pn[192]; Bm1 = pn[256]; Bm2 = pn[320];

        // vector merge (packed fp32): m = c2*2^-12 + c1
        const f32x16 m = c2 * 0x1p-12f + c1;

        // bk select (scalar cmp+cndmask), then packed max update
#pragma unroll
        for (int q = 0; q < 16; ++q) if (m[q] > best[q]) bk[q] = kl;
#pragma unroll
        for (int q = 0; q < 16; ++q) best[q] = fmaxf(best[q], m[q]);

        cn_cur = cn_nxt;
    }

    // ---- cross-lane lexicographic (max m, min k) reduce over 32 cols ----
#pragma unroll
    for (int q = 0; q < 16; ++q) {
        float d = best[q]; int K = bk[q];
#pragma unroll
        for (int mm = 1; mm < 32; mm <<= 1) {
            const float od = __shfl_xor(d, mm, 64);
            const int   ok = __shfl_xor(K, mm, 64);
            const bool tk = (od > d) || (od == d && ok < K);
            d = tk ? od : d; K = tk ? ok : K;
        }
        const int row32 = (q & 3) + 8 * (q >> 2) + 4 * lh;   // verified C-row map
        if ((lane & 31) == q) lds_bk[wid * 32 + row32] = K;
    }
    __syncthreads();

    // ---- gather chosen code (fp32 original), scatter to image layout ----
    const int myk = lds_bk[wid * 32 + col];
    const int b = wbase + col;
    const int by4 = (b >> 9) * 4, bx = b & 511;
    const float4* qp = (const float4*)(cb + (size_t)myk * DD);
#pragma unroll
    for (int rr = 0; rr < 2; ++rr) {
        const int r = lh * 2 + rr;
        float4* op = (float4*)(out + ((size_t)(by4 + r) * 2048 + bx * 4) * 3);
        op[0] = qp[r * 3 + 0];
        op[1] = qp[r * 3 + 1];
        op[2] = qp[r * 3 + 2];
    }
}

extern "C" void kernel_launch(void* const* d_in, const int* in_sizes, int n_in,
                              void* d_out, int out_size, void* d_ws, size_t ws_size,
                              hipStream_t stream) {
    const float* img = (const float*)d_in[0];   // (2048, 2048, 3) fp32
    const float* cb  = (const float*)d_in[1];   // (1024, 16, 3) fp32
    float* out = (float*)d_out;                 // (2048, 2048, 3) fp32
    float* ws  = (float*)d_ws;

    vq_cnorm_kernel<<<(NK + 255) / 256, 256, 0, stream>>>(cb, ws + WS_CNH);
    vq_bprep_kernel<<<(NFRAG_TIDS + 255) / 256, 256, 0, stream>>>(cb, ws);
    vq_mfma_kernel<<<NL / 32 / 4, 256, 0, stream>>>(img, cb, ws, out);
}